// Round 3
// baseline (648.410 us; speedup 1.0000x reference)
//
#include <hip/hip_runtime.h>
#include <hip/hip_fp16.h>
#include <math.h>

#define N_NODES 50000
#define N_EDGES 1200000
#define N_GRAPHS 128
#define D_IN 32
#define D_H 64
#define D_OUT 10
#define ELL_CAP 64

#define EPS 1e-7f
#define MAX_NORM (1.0f - 1e-5f)

// ---------------- wave helpers ----------------

__device__ __forceinline__ float wave_reduce_sum(float v) {
    #pragma unroll
    for (int off = 32; off > 0; off >>= 1)
        v += __shfl_xor(v, off, 64);
    return v;
}

// logmap0(proj(expmap0(u))) on a lane-distributed vector (one component per
// lane; inactive lanes pass 0). Replicates the reference's exact sequence.
__device__ __forceinline__ float exp_proj_log(float m) {
    float n = fmaxf(sqrtf(wave_reduce_sum(m * m)), EPS);
    float v = tanhf(n) * m / n;
    float nv = fmaxf(sqrtf(wave_reduce_sum(v * v)), EPS);
    if (nv > MAX_NORM) v = v * (MAX_NORM / nv);
    float nl = sqrtf(wave_reduce_sum(v * v));
    nl = fminf(fmaxf(nl, EPS), MAX_NORM);
    return atanhf(nl) * v / nl;
}

// ---------------- kernels ----------------

// Build ELL adjacency (ushort src ids): append src[e] to dst[e]'s row.
__global__ void ell_fill_kernel(const int* __restrict__ src, const int* __restrict__ dst,
                                int* __restrict__ deg, ushort* __restrict__ ell, int E) {
    int e = blockIdx.x * 256 + threadIdx.x;
    if (e >= E) return;
    int s = src[e];
    int d = dst[e];
    s = min(max(s, 0), N_NODES - 1);
    d = min(max(d, 0), N_NODES - 1);
    int pos = atomicAdd(&deg[d], 1);
    if (pos < ELL_CAP) ell[d * ELL_CAP + pos] = (ushort)s;
}

// u0 = fp16(logmap0(proj(expmap0(x)))), x: [N, 32]. One wave per node.
__global__ void tangent0_kernel(const float* __restrict__ x, __half* __restrict__ u0, int n) {
    int gid = blockIdx.x * 256 + threadIdx.x;
    int node = gid >> 6;
    int lane = gid & 63;
    if (node >= n) return;
    float m = (lane < D_IN) ? x[node * D_IN + lane] : 0.0f;
    float t = exp_proj_log(m);
    if (lane < D_IN) u0[node * D_IN + lane] = __float2half(t);
}

// Fused HGCN layer: gather-mean over ELL (fp16 source, K dims) -> @W + b
// (exact swap: mean is linear; deg==0 forced to 0 to match segment_mean)
// -> optional leaky_relu -> expmap0 -> proj -> logmap0 -> fp16 store
// (or atomic pool accumulation for the last layer).
// One wave per node (looped); W column held in registers, operand via shfl.
template <int K, int ACT, int POOL>
__global__ __launch_bounds__(256, 4)
void layer_kernel(const __half* __restrict__ uin, const float* __restrict__ W,
                  const float* __restrict__ b, const int* __restrict__ deg,
                  const ushort* __restrict__ ell, __half* __restrict__ uout,
                  const int* __restrict__ batch, float* __restrict__ pooled,
                  float* __restrict__ cntg, int nwaves) {
    int wid = (blockIdx.x * 256 + threadIdx.x) >> 6;
    int lane = threadIdx.x & 63;

    float Wreg[K];
    #pragma unroll
    for (int k = 0; k < K; ++k) Wreg[k] = W[k * 64 + lane];
    float bias = b[lane];

    for (int node = wid; node < N_NODES; node += nwaves) {
        int d_true = deg[node];
        int d = min(d_true, ELL_CAP);
        int id = (lane < d) ? (int)ell[node * ELL_CAP + lane] : 0;
        float acc = 0.0f;
        if (K == 64) {
            int e = 0;
            for (; e + 4 <= d; e += 4) {
                int s0 = __shfl(id, e, 64);
                int s1 = __shfl(id, e + 1, 64);
                int s2 = __shfl(id, e + 2, 64);
                int s3 = __shfl(id, e + 3, 64);
                float v0 = __half2float(uin[s0 * 64 + lane]);
                float v1 = __half2float(uin[s1 * 64 + lane]);
                float v2 = __half2float(uin[s2 * 64 + lane]);
                float v3 = __half2float(uin[s3 * 64 + lane]);
                acc += v0 + v1 + v2 + v3;
            }
            for (; e < d; ++e) {
                int s = __shfl(id, e, 64);
                acc += __half2float(uin[s * 64 + lane]);
            }
        } else {  // K == 32: two edges per step, halves of the wave
            int half = lane >> 5;
            int dim = lane & 31;
            int e = 0;
            for (; e + 2 <= d; e += 2) {
                int s0 = __shfl(id, e, 64);
                int s1 = __shfl(id, e + 1, 64);
                int s = half ? s1 : s0;
                acc += __half2float(uin[s * 32 + dim]);
            }
            if (e < d) {  // wave-uniform branch (d uniform)
                int s = __shfl(id, e, 64);
                if (half == 0) acc += __half2float(uin[s * 32 + dim]);
            }
            acc += __shfl_xor(acc, 32, 64);  // both halves hold full sum per dim
        }
        float m = acc / fmaxf((float)d_true, 1.0f);

        // linear in tangent space (exact: mean commutes with affine map)
        float h = bias;
        #pragma unroll
        for (int k = 0; k < K; ++k)
            h = fmaf(__shfl(m, k, 64), Wreg[k], h);
        if (d_true == 0) h = 0.0f;  // segment_mean of empty segment is 0 (no bias)
        if (ACT) h = (h >= 0.0f) ? h : 0.2f * h;

        float t = exp_proj_log(h);

        if (POOL) {
            int g = min(max(batch[node], 0), N_GRAPHS - 1);
            atomicAdd(&pooled[g * 64 + lane], t);
            if (lane == 0) atomicAdd(&cntg[g], 1.0f);
        } else {
            uout[node * 64 + lane] = __float2half(t);
        }
    }
}

// final head: mean -> exp/proj/log -> @Wl + bl -> expmap0 -> proj
__global__ void head_kernel(const float* __restrict__ pooled, const float* __restrict__ cntg,
                            const float* __restrict__ Wl, const float* __restrict__ bl,
                            float* __restrict__ out) {
    int g = blockIdx.x;
    int lane = threadIdx.x;
    float m = pooled[g * 64 + lane] / fmaxf(cntg[g], 1.0f);
    float z = exp_proj_log(m);
    float acc = 0.0f;
    #pragma unroll
    for (int k = 0; k < 64; ++k) {
        float zk = __shfl(z, k, 64);
        if (lane < D_OUT) acc = fmaf(zk, Wl[k * D_OUT + lane], acc);
    }
    float o = (lane < D_OUT) ? (acc + bl[lane]) : 0.0f;
    float n = fmaxf(sqrtf(wave_reduce_sum(o * o)), EPS);
    float v = tanhf(n) * o / n;
    float nv = fmaxf(sqrtf(wave_reduce_sum(v * v)), EPS);
    if (nv > MAX_NORM) v = v * (MAX_NORM / nv);
    if (lane < D_OUT) out[g * D_OUT + lane] = v;
}

// ---------------- launch ----------------

extern "C" void kernel_launch(void* const* d_in, const int* in_sizes, int n_in,
                              void* d_out, int out_size, void* d_ws, size_t ws_size,
                              hipStream_t stream) {
    const float* x   = (const float*)d_in[0];
    const int* edge  = (const int*)d_in[1];   // [2, E]
    const int* batch = (const int*)d_in[2];
    const float* W1  = (const float*)d_in[3];
    const float* b1  = (const float*)d_in[4];
    const float* W2  = (const float*)d_in[5];
    const float* b2  = (const float*)d_in[6];
    const float* W3  = (const float*)d_in[7];
    const float* b3  = (const float*)d_in[8];
    const float* Wl  = (const float*)d_in[9];
    const float* bl  = (const float*)d_in[10];
    float* out = (float*)d_out;

    const int N = N_NODES, E = N_EDGES, G = N_GRAPHS;
    const int* src = edge;
    const int* dst = edge + E;

    // workspace layout: [deg:int N][pooled:f G*64][cntg:f G][ell:u16 N*64]
    //                   [u0h:h N*32][u1h:h N*64][u2h:h N*64]
    char* ws = (char*)d_ws;
    int*    deg    = (int*)ws;
    float*  pooled = (float*)(deg + N);
    float*  cntg   = pooled + (size_t)G * 64;
    ushort* ell    = (ushort*)(cntg + G);
    __half* u0h    = (__half*)(ell + (size_t)N * ELL_CAP);
    __half* u1h    = u0h + (size_t)N * 32;
    __half* u2h    = u1h + (size_t)N * 64;

    size_t zero_bytes = ((size_t)N + (size_t)G * 64 + G) * 4;
    hipMemsetAsync(d_ws, 0, zero_bytes, stream);

    int blocksE   = (E + 255) / 256;
    int blocksN64 = (N * 64 + 255) / 256;
    const int blocksL = 1024;            // fused layer kernels
    const int nwaves  = blocksL * 4;

    ell_fill_kernel<<<blocksE, 256, 0, stream>>>(src, dst, deg, ell, E);
    tangent0_kernel<<<blocksN64, 256, 0, stream>>>(x, u0h, N);

    // layer 1: gather u0 (K=32) -> @W1+b1 -> lrelu -> epl -> u1h
    layer_kernel<32, 1, 0><<<blocksL, 256, 0, stream>>>(
        u0h, W1, b1, deg, ell, u1h, nullptr, nullptr, nullptr, nwaves);
    // layer 2: gather u1 (K=64) -> @W2+b2 -> lrelu -> epl -> u2h
    layer_kernel<64, 1, 0><<<blocksL, 256, 0, stream>>>(
        u1h, W2, b2, deg, ell, u2h, nullptr, nullptr, nullptr, nwaves);
    // layer 3: gather u2 (K=64) -> @W3+b3 -> epl -> atomic pool
    layer_kernel<64, 0, 1><<<blocksL, 256, 0, stream>>>(
        u2h, W3, b3, deg, ell, nullptr, batch, pooled, cntg, nwaves);

    head_kernel<<<G, 64, 0, stream>>>(pooled, cntg, Wl, bl, out);
}